// Round 1
// baseline (1228.670 us; speedup 1.0000x reference)
//
#include <hip/hip_runtime.h>
#include <math.h>

#define N_NODES 50000
#define N_EDGES 600000
#define HID 128
#define NLAYERS 4
#define NODE_IN 16
#define EDGE_IN 8
#define LN_EPS 1e-5f

// ---------------- edge_index dtype detection (int32 vs int64) ----------------
// If the harness passed int64 (little-endian, values in [0,50000)), every odd
// 32-bit word of the first 1024 "pairs" is 0. For int32 those words are random
// node ids (nonzero with prob ~1-1/50000 each).
__global__ void detect_i64(const int* ei, int* flag) {
    __shared__ int nz;
    if (threadIdx.x == 0) nz = 0;
    __syncthreads();
    int acc = 0;
    for (int i = threadIdx.x; i < 1024; i += blockDim.x)
        if (ei[2 * i + 1] != 0) acc = 1;
    if (acc) atomicOr(&nz, 1);
    __syncthreads();
    if (threadIdx.x == 0) *flag = (nz == 0) ? 1 : 0;
}

__device__ __forceinline__ int edge_src(const void* ei, int f, int e) {
    if (f) return (int)((const long long*)ei)[e];
    return ((const int*)ei)[e];
}
__device__ __forceinline__ int edge_dst(const void* ei, int f, int e) {
    if (f) return (int)((const long long*)ei)[N_EDGES + e];
    return ((const int*)ei)[N_EDGES + e];
}

// ---------------- CSR build: histogram, scan, place ----------------
__global__ void hist_k(const void* ei, const int* flag, int* cursor) {
    int e = blockIdx.x * blockDim.x + threadIdx.x;
    if (e >= N_EDGES) return;
    int f = *flag;
    atomicAdd(&cursor[edge_dst(ei, f, e)], 1);
}

__global__ void scan_k(int* cursor, int* row_ptr) {
    __shared__ int sd[1024];
    __shared__ int s_run;
    int tid = threadIdx.x;
    if (tid == 0) s_run = 0;
    __syncthreads();
    for (int base = 0; base < N_NODES; base += 1024) {
        int i = base + tid;
        int v = (i < N_NODES) ? cursor[i] : 0;
        sd[tid] = v;
        __syncthreads();
        for (int off = 1; off < 1024; off <<= 1) {
            int t = (tid >= off) ? sd[tid - off] : 0;
            __syncthreads();
            sd[tid] += t;
            __syncthreads();
        }
        int incl = sd[tid];
        int run = s_run;
        if (i < N_NODES) {
            int r = run + incl - v;   // exclusive prefix
            row_ptr[i] = r;
            cursor[i] = r;            // cursor for the place pass
        }
        int total = sd[1023];
        __syncthreads();
        if (tid == 0) s_run = run + total;
        __syncthreads();
    }
    if (tid == 0) row_ptr[N_NODES] = s_run;
}

__global__ void place_k(const void* ei, const int* flag, int* cursor,
                        int* sorted_src, int* sorted_eid) {
    int e = blockIdx.x * blockDim.x + threadIdx.x;
    if (e >= N_EDGES) return;
    int f = *flag;
    int s = edge_src(ei, f, e);
    int d = edge_dst(ei, f, e);
    int pos = atomicAdd(&cursor[d], 1);
    sorted_src[pos] = s;
    sorted_eid[pos] = e;
}

// ---------------- per-edge gate y_l = sigmoid(ea . adm_w[l] + adm_b[l]) -----
// One wave (64 lanes) per sorted edge position; lane handles channels c0=lane,
// c1=lane+64 of ea = edge_attr @ edge_w + edge_b, then butterfly-reduce 4 dots.
__global__ __launch_bounds__(256) void ycompute_k(
    const int* __restrict__ sorted_eid, const float* __restrict__ edge_attr,
    const float* __restrict__ edge_w, const float* __restrict__ edge_b,
    const float* __restrict__ adm_w, const float* __restrict__ adm_b,
    float* __restrict__ y_sorted) {
    __shared__ float ew[EDGE_IN * HID];
    __shared__ float ebv[HID];
    __shared__ float aw[NLAYERS * HID];
    for (int i = threadIdx.x; i < EDGE_IN * HID; i += 256) ew[i] = edge_w[i];
    for (int i = threadIdx.x; i < HID; i += 256) ebv[i] = edge_b[i];
    for (int i = threadIdx.x; i < NLAYERS * HID; i += 256) aw[i] = adm_w[i];
    __syncthreads();
    int wid = threadIdx.x >> 6, lane = threadIdx.x & 63;
    int p = blockIdx.x * 4 + wid;
    if (p >= N_EDGES) return;
    int eid = sorted_eid[p];
    const float* ap = edge_attr + (size_t)eid * EDGE_IN;
    int c0 = lane, c1 = lane + 64;
    float ea0 = ebv[c0], ea1 = ebv[c1];
#pragma unroll
    for (int k = 0; k < EDGE_IN; ++k) {
        float a = ap[k];
        ea0 += a * ew[k * HID + c0];
        ea1 += a * ew[k * HID + c1];
    }
    float pr0 = ea0 * aw[0 * HID + c0] + ea1 * aw[0 * HID + c1];
    float pr1 = ea0 * aw[1 * HID + c0] + ea1 * aw[1 * HID + c1];
    float pr2 = ea0 * aw[2 * HID + c0] + ea1 * aw[2 * HID + c1];
    float pr3 = ea0 * aw[3 * HID + c0] + ea1 * aw[3 * HID + c1];
#pragma unroll
    for (int m = 1; m < 64; m <<= 1) {
        pr0 += __shfl_xor(pr0, m, 64);
        pr1 += __shfl_xor(pr1, m, 64);
        pr2 += __shfl_xor(pr2, m, 64);
        pr3 += __shfl_xor(pr3, m, 64);
    }
    if (lane == 0) {
        y_sorted[0 * N_EDGES + p] = 1.0f / (1.0f + expf(-(pr0 + adm_b[0])));
        y_sorted[1 * N_EDGES + p] = 1.0f / (1.0f + expf(-(pr1 + adm_b[1])));
        y_sorted[2 * N_EDGES + p] = 1.0f / (1.0f + expf(-(pr2 + adm_b[2])));
        y_sorted[3 * N_EDGES + p] = 1.0f / (1.0f + expf(-(pr3 + adm_b[3])));
    }
}

// ---------------- h0 = x @ node_w + node_b ----------------
__global__ void node_encode_k(const float* __restrict__ x, const float* __restrict__ nw,
                              const float* __restrict__ nb, float* __restrict__ h) {
    int idx = blockIdx.x * 256 + threadIdx.x;
    if (idx >= N_NODES * HID) return;
    int n = idx >> 7, c = idx & 127;
    float acc = nb[c];
#pragma unroll
    for (int k = 0; k < NODE_IN; ++k) acc += x[n * NODE_IN + k] * nw[k * HID + c];
    h[idx] = acc;
}

// ---------------- tiled GEMM: out[n] = in[n] @ W + bias  (M=50000,K=N=128) ---
// block: 64 nodes x 128 ch; thread (tm=tid>>4, tn=tid&15) owns 4 nodes x 8 ch.
__global__ __launch_bounds__(256) void gemm_hn_k(
    const float* __restrict__ in, const float* __restrict__ W,
    const float* __restrict__ bias, float* __restrict__ out) {
    __shared__ float A[64 * HID];   // 32 KB
    __shared__ float Wt[64 * HID];  // 32 KB (K staged in two chunks)
    const int tid = threadIdx.x;
    const int n0 = blockIdx.x * 64;
    const int tm = tid >> 4, tn = tid & 15;
#pragma unroll
    for (int i = 0; i < 8; ++i) {
        int f4 = tid + i * 256;
        int row = f4 >> 5;
        float4 v = make_float4(0.f, 0.f, 0.f, 0.f);
        if (n0 + row < N_NODES) v = ((const float4*)in)[(size_t)(n0 + row) * 32 + (f4 & 31)];
        ((float4*)A)[f4] = v;
    }
    float acc[4][8];
#pragma unroll
    for (int j = 0; j < 4; ++j)
#pragma unroll
        for (int c = 0; c < 8; ++c) acc[j][c] = 0.f;

#pragma unroll
    for (int kc = 0; kc < 2; ++kc) {
        __syncthreads();
#pragma unroll
        for (int i = 0; i < 8; ++i) {
            int f4 = tid + i * 256;
            ((float4*)Wt)[f4] = ((const float4*)W)[kc * 2048 + f4];
        }
        __syncthreads();
#pragma unroll 8
        for (int k = 0; k < 64; k += 2) {
            float2 av[4];
#pragma unroll
            for (int j = 0; j < 4; ++j)
                av[j] = *(const float2*)&A[(tm * 4 + j) * HID + kc * 64 + k];
            float4 w00 = *(const float4*)&Wt[k * HID + tn * 8];
            float4 w01 = *(const float4*)&Wt[k * HID + tn * 8 + 4];
            float4 w10 = *(const float4*)&Wt[(k + 1) * HID + tn * 8];
            float4 w11 = *(const float4*)&Wt[(k + 1) * HID + tn * 8 + 4];
#pragma unroll
            for (int j = 0; j < 4; ++j) {
                acc[j][0] += av[j].x * w00.x; acc[j][1] += av[j].x * w00.y;
                acc[j][2] += av[j].x * w00.z; acc[j][3] += av[j].x * w00.w;
                acc[j][4] += av[j].x * w01.x; acc[j][5] += av[j].x * w01.y;
                acc[j][6] += av[j].x * w01.z; acc[j][7] += av[j].x * w01.w;
                acc[j][0] += av[j].y * w10.x; acc[j][1] += av[j].y * w10.y;
                acc[j][2] += av[j].y * w10.z; acc[j][3] += av[j].y * w10.w;
                acc[j][4] += av[j].y * w11.x; acc[j][5] += av[j].y * w11.y;
                acc[j][6] += av[j].y * w11.z; acc[j][7] += av[j].y * w11.w;
            }
        }
    }
    float4 b0 = ((const float4*)bias)[tn * 2];
    float4 b1 = ((const float4*)bias)[tn * 2 + 1];
#pragma unroll
    for (int j = 0; j < 4; ++j) {
        int n = n0 + tm * 4 + j;
        if (n < N_NODES) {
            float4 o0 = make_float4(acc[j][0] + b0.x, acc[j][1] + b0.y,
                                    acc[j][2] + b0.z, acc[j][3] + b0.w);
            float4 o1 = make_float4(acc[j][4] + b1.x, acc[j][5] + b1.y,
                                    acc[j][6] + b1.z, acc[j][7] + b1.w);
            ((float4*)out)[(size_t)n * 32 + tn * 2] = o0;
            ((float4*)out)[(size_t)n * 32 + tn * 2 + 1] = o1;
        }
    }
}

// ---------------- per-layer edge pass (CSR, one wave per node) --------------
// Accumulates Ssum[n] = sum y*ea (ea recomputed on the fly, cheap: K=8),
// agg[n] = sum y*hn[src], ssum[n] = sum y.
__global__ __launch_bounds__(256) void edge_pass_k(
    const int* __restrict__ row_ptr, const int* __restrict__ sorted_src,
    const int* __restrict__ sorted_eid, const float* __restrict__ edge_attr,
    const float* __restrict__ edge_w, const float* __restrict__ edge_b,
    const float* __restrict__ y_l, const float* __restrict__ hn,
    float* __restrict__ Ssum, float* __restrict__ ssum, float* __restrict__ agg) {
    __shared__ float ew[EDGE_IN * HID];
    __shared__ float ebv[HID];
    for (int i = threadIdx.x; i < EDGE_IN * HID; i += 256) ew[i] = edge_w[i];
    for (int i = threadIdx.x; i < HID; i += 256) ebv[i] = edge_b[i];
    __syncthreads();
    int wid = threadIdx.x >> 6, lane = threadIdx.x & 63;
    int c0 = lane, c1 = lane + 64;
    float eb0 = ebv[c0], eb1 = ebv[c1];
    for (int n = blockIdx.x * 4 + wid; n < N_NODES; n += gridDim.x * 4) {
        int ps = row_ptr[n], pe = row_ptr[n + 1];
        float aS0 = 0.f, aS1 = 0.f, aH0 = 0.f, aH1 = 0.f, ay = 0.f;
        for (int p = ps; p < pe; ++p) {
            int eid = sorted_eid[p];
            int sn = sorted_src[p];
            float y = y_l[p];
            const float* ap = edge_attr + (size_t)eid * EDGE_IN;
            float ea0 = eb0, ea1 = eb1;
#pragma unroll
            for (int k = 0; k < EDGE_IN; ++k) {
                float a = ap[k];
                ea0 += a * ew[k * HID + c0];
                ea1 += a * ew[k * HID + c1];
            }
            aS0 += y * ea0; aS1 += y * ea1; ay += y;
            aH0 += y * hn[(size_t)sn * HID + c0];
            aH1 += y * hn[(size_t)sn * HID + c1];
        }
        Ssum[(size_t)n * HID + c0] = aS0;
        Ssum[(size_t)n * HID + c1] = aS1;
        agg[(size_t)n * HID + c0] = aH0;
        agg[(size_t)n * HID + c1] = aH1;
        if (lane == 0) ssum[n] = ay;
    }
}

// ------- fused: agg_full = agg + ssum*eb + Ssum@W; LN; h += relu(LN) --------
__global__ __launch_bounds__(256) void gemm_out_ln_k(
    const float* __restrict__ Sin, const float* __restrict__ W,
    const float* __restrict__ eb, const float* __restrict__ agg,
    const float* __restrict__ ssum, const float* __restrict__ gm,
    const float* __restrict__ bt, float* __restrict__ h) {
    __shared__ float A[64 * HID];
    __shared__ float Wt[64 * HID];
    const int tid = threadIdx.x;
    const int n0 = blockIdx.x * 64;
    const int tm = tid >> 4, tn = tid & 15;
#pragma unroll
    for (int i = 0; i < 8; ++i) {
        int f4 = tid + i * 256;
        int row = f4 >> 5;
        float4 v = make_float4(0.f, 0.f, 0.f, 0.f);
        if (n0 + row < N_NODES) v = ((const float4*)Sin)[(size_t)(n0 + row) * 32 + (f4 & 31)];
        ((float4*)A)[f4] = v;
    }
    float4 b0 = ((const float4*)eb)[tn * 2];
    float4 b1 = ((const float4*)eb)[tn * 2 + 1];
    float acc[4][8];
#pragma unroll
    for (int j = 0; j < 4; ++j) {
        int n = n0 + tm * 4 + j;
        if (n < N_NODES) {
            float sy = ssum[n];
            float4 g0 = ((const float4*)agg)[(size_t)n * 32 + tn * 2];
            float4 g1 = ((const float4*)agg)[(size_t)n * 32 + tn * 2 + 1];
            acc[j][0] = g0.x + sy * b0.x; acc[j][1] = g0.y + sy * b0.y;
            acc[j][2] = g0.z + sy * b0.z; acc[j][3] = g0.w + sy * b0.w;
            acc[j][4] = g1.x + sy * b1.x; acc[j][5] = g1.y + sy * b1.y;
            acc[j][6] = g1.z + sy * b1.z; acc[j][7] = g1.w + sy * b1.w;
        } else {
#pragma unroll
            for (int c = 0; c < 8; ++c) acc[j][c] = 0.f;
        }
    }
#pragma unroll
    for (int kc = 0; kc < 2; ++kc) {
        __syncthreads();
#pragma unroll
        for (int i = 0; i < 8; ++i) {
            int f4 = tid + i * 256;
            ((float4*)Wt)[f4] = ((const float4*)W)[kc * 2048 + f4];
        }
        __syncthreads();
#pragma unroll 8
        for (int k = 0; k < 64; k += 2) {
            float2 av[4];
#pragma unroll
            for (int j = 0; j < 4; ++j)
                av[j] = *(const float2*)&A[(tm * 4 + j) * HID + kc * 64 + k];
            float4 w00 = *(const float4*)&Wt[k * HID + tn * 8];
            float4 w01 = *(const float4*)&Wt[k * HID + tn * 8 + 4];
            float4 w10 = *(const float4*)&Wt[(k + 1) * HID + tn * 8];
            float4 w11 = *(const float4*)&Wt[(k + 1) * HID + tn * 8 + 4];
#pragma unroll
            for (int j = 0; j < 4; ++j) {
                acc[j][0] += av[j].x * w00.x; acc[j][1] += av[j].x * w00.y;
                acc[j][2] += av[j].x * w00.z; acc[j][3] += av[j].x * w00.w;
                acc[j][4] += av[j].x * w01.x; acc[j][5] += av[j].x * w01.y;
                acc[j][6] += av[j].x * w01.z; acc[j][7] += av[j].x * w01.w;
                acc[j][0] += av[j].y * w10.x; acc[j][1] += av[j].y * w10.y;
                acc[j][2] += av[j].y * w10.z; acc[j][3] += av[j].y * w10.w;
                acc[j][4] += av[j].y * w11.x; acc[j][5] += av[j].y * w11.y;
                acc[j][6] += av[j].y * w11.z; acc[j][7] += av[j].y * w11.w;
            }
        }
    }
    // LayerNorm over 128 channels (16 threads with same tm hold one node row)
    float4 ga0 = ((const float4*)gm)[tn * 2], ga1 = ((const float4*)gm)[tn * 2 + 1];
    float4 be0 = ((const float4*)bt)[tn * 2], be1 = ((const float4*)bt)[tn * 2 + 1];
#pragma unroll
    for (int j = 0; j < 4; ++j) {
        float s = acc[j][0] + acc[j][1] + acc[j][2] + acc[j][3] +
                  acc[j][4] + acc[j][5] + acc[j][6] + acc[j][7];
        s += __shfl_xor(s, 1, 64); s += __shfl_xor(s, 2, 64);
        s += __shfl_xor(s, 4, 64); s += __shfl_xor(s, 8, 64);
        float mean = s * (1.0f / HID);
        float d[8];
        float vs = 0.f;
#pragma unroll
        for (int c = 0; c < 8; ++c) { d[c] = acc[j][c] - mean; vs += d[c] * d[c]; }
        vs += __shfl_xor(vs, 1, 64); vs += __shfl_xor(vs, 2, 64);
        vs += __shfl_xor(vs, 4, 64); vs += __shfl_xor(vs, 8, 64);
        float rstd = rsqrtf(vs * (1.0f / HID) + LN_EPS);
        int n = n0 + tm * 4 + j;
        if (n < N_NODES) {
            float4 h0 = ((const float4*)h)[(size_t)n * 32 + tn * 2];
            float4 h1 = ((const float4*)h)[(size_t)n * 32 + tn * 2 + 1];
            h0.x += fmaxf(d[0] * rstd * ga0.x + be0.x, 0.f);
            h0.y += fmaxf(d[1] * rstd * ga0.y + be0.y, 0.f);
            h0.z += fmaxf(d[2] * rstd * ga0.z + be0.z, 0.f);
            h0.w += fmaxf(d[3] * rstd * ga0.w + be0.w, 0.f);
            h1.x += fmaxf(d[4] * rstd * ga1.x + be1.x, 0.f);
            h1.y += fmaxf(d[5] * rstd * ga1.y + be1.y, 0.f);
            h1.z += fmaxf(d[6] * rstd * ga1.z + be1.z, 0.f);
            h1.w += fmaxf(d[7] * rstd * ga1.w + be1.w, 0.f);
            ((float4*)h)[(size_t)n * 32 + tn * 2] = h0;
            ((float4*)h)[(size_t)n * 32 + tn * 2 + 1] = h1;
        }
    }
}

extern "C" void kernel_launch(void* const* d_in, const int* in_sizes, int n_in,
                              void* d_out, int out_size, void* d_ws, size_t ws_size,
                              hipStream_t stream) {
    const float* x         = (const float*)d_in[0];
    const void*  ei        = d_in[1];
    const float* edge_attr = (const float*)d_in[2];
    const float* node_w    = (const float*)d_in[3];
    const float* node_b    = (const float*)d_in[4];
    const float* edge_w    = (const float*)d_in[5];
    const float* edge_b    = (const float*)d_in[6];
    const float* lnode_w   = (const float*)d_in[7];
    const float* lnode_b   = (const float*)d_in[8];
    const float* ledge_w   = (const float*)d_in[9];
    const float* ledge_b   = (const float*)d_in[10];
    const float* adm_w     = (const float*)d_in[11];
    const float* adm_b     = (const float*)d_in[12];
    const float* gamma     = (const float*)d_in[13];
    const float* beta      = (const float*)d_in[14];
    float* h = (float*)d_out;

    char* wp = (char*)d_ws;
    auto alloc = [&](size_t bytes) -> void* {
        void* p = (void*)wp;
        wp += (bytes + 255) & ~(size_t)255;
        return p;
    };
    int*   flag       = (int*)alloc(256);
    int*   cursor     = (int*)alloc(sizeof(int) * N_NODES);
    int*   row_ptr    = (int*)alloc(sizeof(int) * (N_NODES + 1));
    int*   sorted_src = (int*)alloc(sizeof(int) * N_EDGES);
    int*   sorted_eid = (int*)alloc(sizeof(int) * N_EDGES);
    float* y_sorted   = (float*)alloc(sizeof(float) * NLAYERS * N_EDGES);
    float* hn         = (float*)alloc(sizeof(float) * (size_t)N_NODES * HID);
    float* Ssum       = (float*)alloc(sizeof(float) * (size_t)N_NODES * HID);
    float* ssum       = (float*)alloc(sizeof(float) * N_NODES);
    float* agg        = (float*)alloc(sizeof(float) * (size_t)N_NODES * HID);
    (void)ws_size; (void)in_sizes; (void)n_in; (void)out_size;

    hipMemsetAsync(cursor, 0, sizeof(int) * N_NODES, stream);
    detect_i64<<<1, 256, 0, stream>>>((const int*)ei, flag);
    hist_k<<<(N_EDGES + 255) / 256, 256, 0, stream>>>(ei, flag, cursor);
    scan_k<<<1, 1024, 0, stream>>>(cursor, row_ptr);
    place_k<<<(N_EDGES + 255) / 256, 256, 0, stream>>>(ei, flag, cursor, sorted_src, sorted_eid);
    ycompute_k<<<(N_EDGES + 3) / 4, 256, 0, stream>>>(sorted_eid, edge_attr, edge_w, edge_b,
                                                      adm_w, adm_b, y_sorted);
    node_encode_k<<<(N_NODES * HID + 255) / 256, 256, 0, stream>>>(x, node_w, node_b, h);

    for (int l = 0; l < NLAYERS; ++l) {
        gemm_hn_k<<<(N_NODES + 63) / 64, 256, 0, stream>>>(
            h, lnode_w + (size_t)l * HID * HID, lnode_b + (size_t)l * HID, hn);
        edge_pass_k<<<2048, 256, 0, stream>>>(
            row_ptr, sorted_src, sorted_eid, edge_attr, edge_w, edge_b,
            y_sorted + (size_t)l * N_EDGES, hn, Ssum, ssum, agg);
        gemm_out_ln_k<<<(N_NODES + 63) / 64, 256, 0, stream>>>(
            Ssum, ledge_w + (size_t)l * HID * HID, ledge_b + (size_t)l * HID,
            agg, ssum, gamma + (size_t)l * HID, beta + (size_t)l * HID, h);
    }
}